// Round 1
// baseline (791.989 us; speedup 1.0000x reference)
//
#include <hip/hip_runtime.h>

typedef __bf16 bf16x8 __attribute__((ext_vector_type(8)));
typedef float f32x16 __attribute__((ext_vector_type(16)));

#define DEV static __device__ __forceinline__
#define MFMA(a, b, c) __builtin_amdgcn_mfma_f32_32x32x16_bf16((a), (b), (c), 0, 0, 0)

DEV unsigned short f2bf(float f) {
  unsigned u = __float_as_uint(f);
  unsigned r = u + 0x7fffu + ((u >> 16) & 1u);
  return (unsigned short)(r >> 16);
}
DEV float bflo(unsigned u) { return __uint_as_float(u << 16); }
DEV float bfhi(unsigned u) { return __uint_as_float(u & 0xffff0000u); }

DEV f32x16 zero16() {
  f32x16 z;
#pragma unroll
  for (int i = 0; i < 16; i++) z[i] = 0.f;
  return z;
}

// LDS fragment read helpers. Rows are XOR-swizzled by granule^(row&7).
// 256B rows (128 ushorts, 16 granules of 16B)
DEV bf16x8 frag256(const unsigned short* lds, int rowbase, int l, int kk) {
  int row = rowbase + (l & 31);
  int gran = (kk << 1) + (l >> 5);
  return *reinterpret_cast<const bf16x8*>(&lds[row * 128 + ((gran ^ (row & 7)) << 3)]);
}
// 128B rows (64 ushorts, 8 granules)
DEV bf16x8 frag128(const unsigned short* lds, int rowbase, int l, int kk) {
  int row = rowbase + (l & 31);
  int gran = (kk << 1) + (l >> 5);
  return *reinterpret_cast<const bf16x8*>(&lds[row * 64 + ((gran ^ (row & 7)) << 3)]);
}

// ---------------- transpose + f32->bf16 convert: in[R][C] f32 -> out[C][R] bf16
__global__ void k_transpose(const float* __restrict__ in, unsigned short* __restrict__ out,
                            int R, int C) {
  __shared__ float t[32][33];
  int tx = threadIdx.x, ty = threadIdx.y;
  int c0 = blockIdx.x * 32, r0 = blockIdx.y * 32;
#pragma unroll
  for (int i = 0; i < 4; i++)
    t[ty + i * 8][tx] = in[(size_t)(r0 + ty + i * 8) * C + c0 + tx];
  __syncthreads();
#pragma unroll
  for (int i = 0; i < 4; i++)
    out[(size_t)(c0 + ty + i * 8) * R + r0 + tx] = f2bf(t[tx][ty + i * 8]);
}

// ---------------- build Wqkv_t [384][128] (rows: Q 0-127, K 128-255, V 256-383) and Wo_t [128][128]
__global__ void k_build_qkvo(const float* __restrict__ Wq, const float* __restrict__ Wk,
                             const float* __restrict__ Wv, const float* __restrict__ Wo,
                             unsigned short* __restrict__ qkvt, unsigned short* __restrict__ wot) {
  int gid = blockIdx.x * 256 + threadIdx.x;
  if (gid < 49152) {
    int row = gid >> 7, e = gid & 127;
    int mi = row >> 7, c = row & 127, h = c >> 4, d = c & 15;
    const float* W = (mi == 0) ? Wq : (mi == 1) ? Wk : Wv;
    qkvt[gid] = f2bf(W[(h * 128 + e) * 16 + d]);
  } else {
    int id = gid - 49152;
    int n = id >> 7, k = id & 127;
    wot[id] = f2bf(Wo[k * 128 + n]);
  }
}

// ---------------- LayerNorm: one wave per 128-wide row, out bf16
__global__ void k_ln(const float* __restrict__ x, const float* __restrict__ g,
                     const float* __restrict__ b, unsigned short* __restrict__ out) {
  int row = blockIdx.x * 4 + (threadIdx.x >> 6);
  int l = threadIdx.x & 63;
  const float* xr = x + (size_t)row * 128;
  float x0 = xr[l * 2], x1v = xr[l * 2 + 1];
  float s = x0 + x1v;
#pragma unroll
  for (int m = 1; m < 64; m <<= 1) s += __shfl_xor(s, m, 64);
  float mu = s * 0.0078125f;
  float d0 = x0 - mu, d1 = x1v - mu;
  float ss = d0 * d0 + d1 * d1;
#pragma unroll
  for (int m = 1; m < 64; m <<= 1) ss += __shfl_xor(ss, m, 64);
  float inv = rsqrtf(ss * 0.0078125f + 1e-5f);
  float y0 = d0 * inv * g[l * 2] + b[l * 2];
  float y1 = d1 * inv * g[l * 2 + 1] + b[l * 2 + 1];
  unsigned u = ((unsigned)f2bf(y1) << 16) | (unsigned)f2bf(y0);
  *reinterpret_cast<unsigned*>(out + (size_t)row * 128 + l * 2) = u;
}

// ---------------- QKV projection: [4096,128] @ Wqkvt^T -> q/k/v in [bh][t][16] layout
__global__ void k_gemm_qkv(const unsigned short* __restrict__ A, const unsigned short* __restrict__ Bt,
                           unsigned short* __restrict__ qkv) {
  __shared__ __align__(16) unsigned short As[128 * 128];
  __shared__ __align__(16) unsigned short Bs[128 * 128];
  int tid = threadIdx.x;
  int m0 = blockIdx.x * 128, n0 = blockIdx.y * 128;
  int sg = tid & 15, sr = tid >> 4;
#pragma unroll
  for (int i = 0; i < 8; i++) {
    int r = sr + i * 16;
    *reinterpret_cast<bf16x8*>(&As[r * 128 + ((sg ^ (r & 7)) << 3)]) =
        *reinterpret_cast<const bf16x8*>(A + (size_t)(m0 + r) * 128 + sg * 8);
    *reinterpret_cast<bf16x8*>(&Bs[r * 128 + ((sg ^ (r & 7)) << 3)]) =
        *reinterpret_cast<const bf16x8*>(Bt + (size_t)(n0 + r) * 128 + sg * 8);
  }
  __syncthreads();
  int l = tid & 63, w = tid >> 6, wmi = w >> 1, wni = w & 1;
  int ln = l & 31, hi = l >> 5;
  f32x16 acc[2][2];
  acc[0][0] = zero16(); acc[0][1] = zero16(); acc[1][0] = zero16(); acc[1][1] = zero16();
#pragma unroll
  for (int kk = 0; kk < 8; kk++) {
    bf16x8 a0 = frag256(As, wmi * 64, l, kk);
    bf16x8 a1 = frag256(As, wmi * 64 + 32, l, kk);
    bf16x8 b0 = frag256(Bs, wni * 64, l, kk);
    bf16x8 b1 = frag256(Bs, wni * 64 + 32, l, kk);
    acc[0][0] = MFMA(a0, b0, acc[0][0]);
    acc[0][1] = MFMA(a0, b1, acc[0][1]);
    acc[1][0] = MFMA(a1, b0, acc[1][0]);
    acc[1][1] = MFMA(a1, b1, acc[1][1]);
  }
  unsigned short* mat = qkv + (size_t)blockIdx.y * 524288;
#pragma unroll
  for (int im = 0; im < 2; im++)
#pragma unroll
    for (int in_ = 0; in_ < 2; in_++) {
      int c = wni * 64 + in_ * 32 + ln;
      int h = c >> 4, d = c & 15;
#pragma unroll
      for (int r = 0; r < 16; r++) {
        int m = m0 + wmi * 64 + im * 32 + (r & 3) + ((r >> 2) << 3) + (hi << 2);
        int bb = m >> 11, tt = m & 2047;
        mat[((size_t)((bb << 3) + h) * 2048 + tt) * 16 + d] = f2bf(acc[im][in_][r]);
      }
    }
}

// ---------------- per-thread VALU flash attention. scale E^-0.5, log2-domain softmax.
__global__ void k_attn(const unsigned short* __restrict__ qw, const unsigned short* __restrict__ kw,
                       const unsigned short* __restrict__ vw, unsigned short* __restrict__ ow) {
  __shared__ __align__(16) unsigned k_lds[128][8];
  __shared__ __align__(16) unsigned v_lds[128][8];
  int tid = threadIdx.x;
  int qb = blockIdx.x, bh = blockIdx.y;
  int t = qb * 128 + tid;
  const unsigned* qp = reinterpret_cast<const unsigned*>(qw + ((size_t)bh * 2048 + t) * 16);
  const float SC = 0.08838834764831845f * 1.4426950408889634f;  // E^-0.5 * log2(e)
  float qf[16];
#pragma unroll
  for (int i = 0; i < 8; i++) {
    unsigned u = qp[i];
    qf[2 * i] = bflo(u) * SC;
    qf[2 * i + 1] = bfhi(u) * SC;
  }
  float m2 = -1e30f, lsum = 0.f, acc[16];
#pragma unroll
  for (int i = 0; i < 16; i++) acc[i] = 0.f;
  int ntile = qb + 1;
  for (int st = 0; st < ntile; st++) {
    int s0 = st * 128;
    {
      const uint4* kp = reinterpret_cast<const uint4*>(kw + ((size_t)bh * 2048 + s0 + tid) * 16);
      const uint4* vp = reinterpret_cast<const uint4*>(vw + ((size_t)bh * 2048 + s0 + tid) * 16);
      *reinterpret_cast<uint4*>(&k_lds[tid][0]) = kp[0];
      *reinterpret_cast<uint4*>(&k_lds[tid][4]) = kp[1];
      *reinterpret_cast<uint4*>(&v_lds[tid][0]) = vp[0];
      *reinterpret_cast<uint4*>(&v_lds[tid][4]) = vp[1];
    }
    __syncthreads();
    int cnt = t - s0 + 1;
    if (cnt > 128) cnt = 128;
    for (int j = 0; j < cnt; j++) {
      uint4 k0 = *reinterpret_cast<const uint4*>(&k_lds[j][0]);
      uint4 k1 = *reinterpret_cast<const uint4*>(&k_lds[j][4]);
      float dot = 0.f;
      dot = fmaf(qf[0], bflo(k0.x), dot);  dot = fmaf(qf[1], bfhi(k0.x), dot);
      dot = fmaf(qf[2], bflo(k0.y), dot);  dot = fmaf(qf[3], bfhi(k0.y), dot);
      dot = fmaf(qf[4], bflo(k0.z), dot);  dot = fmaf(qf[5], bfhi(k0.z), dot);
      dot = fmaf(qf[6], bflo(k0.w), dot);  dot = fmaf(qf[7], bfhi(k0.w), dot);
      dot = fmaf(qf[8], bflo(k1.x), dot);  dot = fmaf(qf[9], bfhi(k1.x), dot);
      dot = fmaf(qf[10], bflo(k1.y), dot); dot = fmaf(qf[11], bfhi(k1.y), dot);
      dot = fmaf(qf[12], bflo(k1.z), dot); dot = fmaf(qf[13], bfhi(k1.z), dot);
      dot = fmaf(qf[14], bflo(k1.w), dot); dot = fmaf(qf[15], bfhi(k1.w), dot);
      if (dot > m2) {
        float corr = exp2f(m2 - dot);
        lsum *= corr;
#pragma unroll
        for (int i = 0; i < 16; i++) acc[i] *= corr;
        m2 = dot;
      }
      float p = exp2f(dot - m2);
      lsum += p;
      uint4 v0 = *reinterpret_cast<const uint4*>(&v_lds[j][0]);
      uint4 v1 = *reinterpret_cast<const uint4*>(&v_lds[j][4]);
      acc[0] = fmaf(p, bflo(v0.x), acc[0]);   acc[1] = fmaf(p, bfhi(v0.x), acc[1]);
      acc[2] = fmaf(p, bflo(v0.y), acc[2]);   acc[3] = fmaf(p, bfhi(v0.y), acc[3]);
      acc[4] = fmaf(p, bflo(v0.z), acc[4]);   acc[5] = fmaf(p, bfhi(v0.z), acc[5]);
      acc[6] = fmaf(p, bflo(v0.w), acc[6]);   acc[7] = fmaf(p, bfhi(v0.w), acc[7]);
      acc[8] = fmaf(p, bflo(v1.x), acc[8]);   acc[9] = fmaf(p, bfhi(v1.x), acc[9]);
      acc[10] = fmaf(p, bflo(v1.y), acc[10]); acc[11] = fmaf(p, bfhi(v1.y), acc[11]);
      acc[12] = fmaf(p, bflo(v1.z), acc[12]); acc[13] = fmaf(p, bfhi(v1.z), acc[13]);
      acc[14] = fmaf(p, bflo(v1.w), acc[14]); acc[15] = fmaf(p, bfhi(v1.w), acc[15]);
    }
    __syncthreads();
  }
  float rl = 1.0f / lsum;
  int b = bh >> 3, h = bh & 7;
  unsigned short* op = ow + ((size_t)(b * 2048) + t) * 128 + h * 16;
#pragma unroll
  for (int i = 0; i < 8; i++) {
    unsigned u = ((unsigned)f2bf(acc[2 * i + 1] * rl) << 16) | (unsigned)f2bf(acc[2 * i] * rl);
    reinterpret_cast<unsigned*>(op)[i] = u;
  }
}

// ---------------- output projection + residual: x1 = x + o@Wo + bo ; out = x1 + bf2
__global__ void k_gemm_proj(const unsigned short* __restrict__ A, const unsigned short* __restrict__ Bt,
                            const float* __restrict__ bo, const float* __restrict__ x,
                            const float* __restrict__ bf2, float* __restrict__ x1,
                            float* __restrict__ outp) {
  __shared__ __align__(16) unsigned short As[128 * 128];
  __shared__ __align__(16) unsigned short Bs[128 * 128];
  int tid = threadIdx.x;
  int m0 = blockIdx.x * 128;
  int sg = tid & 15, sr = tid >> 4;
#pragma unroll
  for (int i = 0; i < 8; i++) {
    int r = sr + i * 16;
    *reinterpret_cast<bf16x8*>(&As[r * 128 + ((sg ^ (r & 7)) << 3)]) =
        *reinterpret_cast<const bf16x8*>(A + (size_t)(m0 + r) * 128 + sg * 8);
    *reinterpret_cast<bf16x8*>(&Bs[r * 128 + ((sg ^ (r & 7)) << 3)]) =
        *reinterpret_cast<const bf16x8*>(Bt + (size_t)r * 128 + sg * 8);
  }
  __syncthreads();
  int l = tid & 63, w = tid >> 6, wmi = w >> 1, wni = w & 1;
  int ln = l & 31, hi = l >> 5;
  f32x16 acc[2][2];
  acc[0][0] = zero16(); acc[0][1] = zero16(); acc[1][0] = zero16(); acc[1][1] = zero16();
#pragma unroll
  for (int kk = 0; kk < 8; kk++) {
    bf16x8 a0 = frag256(As, wmi * 64, l, kk);
    bf16x8 a1 = frag256(As, wmi * 64 + 32, l, kk);
    bf16x8 b0 = frag256(Bs, wni * 64, l, kk);
    bf16x8 b1 = frag256(Bs, wni * 64 + 32, l, kk);
    acc[0][0] = MFMA(a0, b0, acc[0][0]);
    acc[0][1] = MFMA(a0, b1, acc[0][1]);
    acc[1][0] = MFMA(a1, b0, acc[1][0]);
    acc[1][1] = MFMA(a1, b1, acc[1][1]);
  }
#pragma unroll
  for (int im = 0; im < 2; im++)
#pragma unroll
    for (int in_ = 0; in_ < 2; in_++) {
      int n = wni * 64 + in_ * 32 + ln;
      float bon = bo[n], b2n = bf2[n];
#pragma unroll
      for (int r = 0; r < 16; r++) {
        int m = m0 + wmi * 64 + im * 32 + (r & 3) + ((r >> 2) << 3) + (hi << 2);
        float v = acc[im][in_][r] + bon;
        float xv = x[(size_t)m * 128 + n] + v;
        x1[(size_t)m * 128 + n] = xv;
        outp[(size_t)m * 128 + n] = xv + b2n;
      }
    }
}

// ---------------- fused FFN: out += relu(h2@W1+bf1)@W2 ; split-K over hidden with atomics
__global__ void __launch_bounds__(256, 2)
k_ffn(const unsigned short* __restrict__ h2, const unsigned short* __restrict__ w1t,
      const unsigned short* __restrict__ w2t, const float* __restrict__ bf1,
      float* __restrict__ outp) {
  __shared__ __align__(16) unsigned short w1_lds[64 * 128];   // [n 64][k 128] swizzled
  __shared__ __align__(16) unsigned short w2_lds[128 * 64];   // [e 128][k 64] swizzled
  __shared__ __align__(16) unsigned short g_lds[128 * 64];    // [m 128][n 64] swizzled
  int tid = threadIdx.x, l = tid & 63, w = tid >> 6;
  int wmi = w >> 1, wni = w & 1;
  int ln = l & 31, hi = l >> 5;
  int chunk = blockIdx.x & 15, rowblk = blockIdx.x >> 4;

  // hoisted h2 A-fragments (constant across the hidden loop)
  bf16x8 af[2][8];
#pragma unroll
  for (int im = 0; im < 2; im++) {
    int row = rowblk * 128 + wmi * 64 + im * 32 + ln;
#pragma unroll
    for (int kk = 0; kk < 8; kk++)
      af[im][kk] = *reinterpret_cast<const bf16x8*>(h2 + (size_t)row * 128 + kk * 16 + hi * 8);
  }

  f32x16 acc2[2][2];
  acc2[0][0] = zero16(); acc2[0][1] = zero16(); acc2[1][0] = zero16(); acc2[1][1] = zero16();

  int sg1 = tid & 15, sr1 = tid >> 4;  // W1 staging: 16 granules x 16 row-groups
  int sg2 = tid & 7, sr2 = tid >> 3;   // W2 staging: 8 granules x 32 row-groups

  for (int it = 0; it < 64; it++) {
    int hid0 = chunk * 4096 + it * 64;
#pragma unroll
    for (int i = 0; i < 4; i++) {
      int r = sr1 + i * 16;
      *reinterpret_cast<bf16x8*>(&w1_lds[r * 128 + ((sg1 ^ (r & 7)) << 3)]) =
          *reinterpret_cast<const bf16x8*>(w1t + (size_t)(hid0 + r) * 128 + sg1 * 8);
    }
#pragma unroll
    for (int i = 0; i < 4; i++) {
      int r = sr2 + i * 32;
      *reinterpret_cast<bf16x8*>(&w2_lds[r * 64 + ((sg2 ^ (r & 7)) << 3)]) =
          *reinterpret_cast<const bf16x8*>(w2t + (size_t)r * 65536 + hid0 + sg2 * 8);
    }
    __syncthreads();

    // GEMM1: G[m, n] = h2 @ W1chunk ; wave covers rows [wmi*64,+64) x cols [wni*32,+32)
    f32x16 acc1[2];
    acc1[0] = zero16(); acc1[1] = zero16();
#pragma unroll
    for (int kk = 0; kk < 8; kk++) {
      bf16x8 b = frag256(w1_lds, wni * 32, l, kk);
      acc1[0] = MFMA(af[0][kk], b, acc1[0]);
      acc1[1] = MFMA(af[1][kk], b, acc1[1]);
    }
    // bias + relu + bf16 -> G tile
    float b1v = bf1[hid0 + wni * 32 + ln];
    int gn = wni * 32 + ln;
    int ggr = gn >> 3, gof = gn & 7;
#pragma unroll
    for (int im = 0; im < 2; im++) {
#pragma unroll
      for (int r = 0; r < 16; r++) {
        int m = wmi * 64 + im * 32 + (r & 3) + ((r >> 2) << 3) + (hi << 2);
        float v = acc1[im][r] + b1v;
        v = v > 0.f ? v : 0.f;
        g_lds[m * 64 + ((ggr ^ (m & 7)) << 3) + gof] = f2bf(v);
      }
    }
    __syncthreads();

    // GEMM2: acc2 += G @ W2chunk
#pragma unroll
    for (int kk = 0; kk < 4; kk++) {
      bf16x8 a0 = frag128(g_lds, wmi * 64, l, kk);
      bf16x8 a1 = frag128(g_lds, wmi * 64 + 32, l, kk);
      bf16x8 b0 = frag128(w2_lds, wni * 64, l, kk);
      bf16x8 b1 = frag128(w2_lds, wni * 64 + 32, l, kk);
      acc2[0][0] = MFMA(a0, b0, acc2[0][0]);
      acc2[0][1] = MFMA(a0, b1, acc2[0][1]);
      acc2[1][0] = MFMA(a1, b0, acc2[1][0]);
      acc2[1][1] = MFMA(a1, b1, acc2[1][1]);
    }
    __syncthreads();
  }

#pragma unroll
  for (int im = 0; im < 2; im++)
#pragma unroll
    for (int in_ = 0; in_ < 2; in_++) {
      int n = wni * 64 + in_ * 32 + ln;
#pragma unroll
      for (int r = 0; r < 16; r++) {
        int m = rowblk * 128 + wmi * 64 + im * 32 + (r & 3) + ((r >> 2) << 3) + (hi << 2);
        atomicAdd(&outp[(size_t)m * 128 + n], acc2[im][in_][r]);
      }
    }
}

extern "C" void kernel_launch(void* const* d_in, const int* in_sizes, int n_in,
                              void* d_out, int out_size, void* d_ws, size_t ws_size,
                              hipStream_t stream) {
  (void)in_sizes; (void)n_in; (void)out_size; (void)ws_size;
  const float* x = (const float*)d_in[0];
  const float* Wk = (const float*)d_in[1];
  const float* Wq = (const float*)d_in[2];
  const float* Wv = (const float*)d_in[3];
  const float* Wo = (const float*)d_in[4];
  const float* bo = (const float*)d_in[5];
  const float* g1 = (const float*)d_in[6];
  const float* be1 = (const float*)d_in[7];
  const float* g2 = (const float*)d_in[8];
  const float* be2 = (const float*)d_in[9];
  const float* W1 = (const float*)d_in[10];
  const float* bf1 = (const float*)d_in[11];
  const float* W2 = (const float*)d_in[12];
  const float* bf2 = (const float*)d_in[13];
  float* outp = (float*)d_out;

  unsigned short* ws = (unsigned short*)d_ws;
  unsigned short* W1t = ws;                       // [65536][128] bf16
  unsigned short* W2t = ws + 8388608;             // [128][65536] bf16
  unsigned short* Wqkvt = ws + 16777216;          // [384][128]
  unsigned short* Wot = ws + 16826368;            // [128][128]
  unsigned short* h1 = ws + 16842752;             // [4096][128]
  unsigned short* h2 = ws + 17367040;             // [4096][128]
  unsigned short* qw = ws + 17891328;             // [16][2048][16]
  unsigned short* kw = ws + 18415616;
  unsigned short* vw = ws + 18939904;
  unsigned short* ow = ws + 19464192;             // [4096][128]
  float* x1 = (float*)(ws + 19988480);            // [4096][128] f32

  k_transpose<<<dim3(2048, 4), dim3(32, 8), 0, stream>>>(W1, W1t, 128, 65536);
  k_transpose<<<dim3(4, 2048), dim3(32, 8), 0, stream>>>(W2, W2t, 65536, 128);
  k_build_qkvo<<<256, 256, 0, stream>>>(Wq, Wk, Wv, Wo, Wqkvt, Wot);
  k_ln<<<1024, 256, 0, stream>>>(x, g1, be1, h1);
  k_gemm_qkv<<<dim3(32, 3), 256, 0, stream>>>(h1, Wqkvt, qw);
  k_attn<<<dim3(16, 16), 128, 0, stream>>>(qw, kw, vw, ow);
  k_gemm_proj<<<32, 256, 0, stream>>>(ow, Wot, bo, x, bf2, x1, outp);
  k_ln<<<1024, 256, 0, stream>>>(x1, g2, be2, h2);
  k_ffn<<<512, 256, 0, stream>>>(h2, W1t, W2t, bf1, outp);
}

// Round 3
// 394.165 us; speedup vs baseline: 2.0093x; 2.0093x over previous
//
#include <hip/hip_runtime.h>

typedef __bf16 bf16x8 __attribute__((ext_vector_type(8)));
typedef float f32x16 __attribute__((ext_vector_type(16)));

#define DEV static __device__ __forceinline__
#define MFMA(a, b, c) __builtin_amdgcn_mfma_f32_32x32x16_bf16((a), (b), (c), 0, 0, 0)

DEV unsigned short f2bf(float f) {
  unsigned u = __float_as_uint(f);
  unsigned r = u + 0x7fffu + ((u >> 16) & 1u);
  return (unsigned short)(r >> 16);
}
DEV float bflo(unsigned u) { return __uint_as_float(u << 16); }
DEV float bfhi(unsigned u) { return __uint_as_float(u & 0xffff0000u); }

DEV f32x16 zero16() {
  f32x16 z;
#pragma unroll
  for (int i = 0; i < 16; i++) z[i] = 0.f;
  return z;
}

// LDS fragment read helpers. Rows are XOR-swizzled by granule^(row&7).
DEV bf16x8 frag256(const unsigned short* lds, int rowbase, int l, int kk) {
  int row = rowbase + (l & 31);
  int gran = (kk << 1) + (l >> 5);
  return *reinterpret_cast<const bf16x8*>(&lds[row * 128 + ((gran ^ (row & 7)) << 3)]);
}
DEV bf16x8 frag128(const unsigned short* lds, int rowbase, int l, int kk) {
  int row = rowbase + (l & 31);
  int gran = (kk << 1) + (l >> 5);
  return *reinterpret_cast<const bf16x8*>(&lds[row * 64 + ((gran ^ (row & 7)) << 3)]);
}

// ---------------- transpose + f32->bf16 convert: in[R][C] f32 -> out[C][R] bf16
__global__ void k_transpose(const float* __restrict__ in, unsigned short* __restrict__ out,
                            int R, int C) {
  __shared__ float t[32][33];
  int tx = threadIdx.x, ty = threadIdx.y;
  int c0 = blockIdx.x * 32, r0 = blockIdx.y * 32;
#pragma unroll
  for (int i = 0; i < 4; i++)
    t[ty + i * 8][tx] = in[(size_t)(r0 + ty + i * 8) * C + c0 + tx];
  __syncthreads();
#pragma unroll
  for (int i = 0; i < 4; i++)
    out[(size_t)(c0 + ty + i * 8) * R + r0 + tx] = f2bf(t[tx][ty + i * 8]);
}

// ---------------- build Wqkv_t [384][128] and Wo_t [128][128]
__global__ void k_build_qkvo(const float* __restrict__ Wq, const float* __restrict__ Wk,
                             const float* __restrict__ Wv, const float* __restrict__ Wo,
                             unsigned short* __restrict__ qkvt, unsigned short* __restrict__ wot) {
  int gid = blockIdx.x * 256 + threadIdx.x;
  if (gid < 49152) {
    int row = gid >> 7, e = gid & 127;
    int mi = row >> 7, c = row & 127, h = c >> 4, d = c & 15;
    const float* W = (mi == 0) ? Wq : (mi == 1) ? Wk : Wv;
    qkvt[gid] = f2bf(W[(h * 128 + e) * 16 + d]);
  } else {
    int id = gid - 49152;
    int n = id >> 7, k = id & 127;
    wot[id] = f2bf(Wo[k * 128 + n]);
  }
}

// ---------------- LayerNorm: one wave per 128-wide row, out bf16
__global__ void k_ln(const float* __restrict__ x, const float* __restrict__ g,
                     const float* __restrict__ b, unsigned short* __restrict__ out) {
  int row = blockIdx.x * 4 + (threadIdx.x >> 6);
  int l = threadIdx.x & 63;
  const float* xr = x + (size_t)row * 128;
  float x0 = xr[l * 2], x1v = xr[l * 2 + 1];
  float s = x0 + x1v;
#pragma unroll
  for (int m = 1; m < 64; m <<= 1) s += __shfl_xor(s, m, 64);
  float mu = s * 0.0078125f;
  float d0 = x0 - mu, d1 = x1v - mu;
  float ss = d0 * d0 + d1 * d1;
#pragma unroll
  for (int m = 1; m < 64; m <<= 1) ss += __shfl_xor(ss, m, 64);
  float inv = rsqrtf(ss * 0.0078125f + 1e-5f);
  float y0 = d0 * inv * g[l * 2] + b[l * 2];
  float y1 = d1 * inv * g[l * 2 + 1] + b[l * 2 + 1];
  unsigned u = ((unsigned)f2bf(y1) << 16) | (unsigned)f2bf(y0);
  *reinterpret_cast<unsigned*>(out + (size_t)row * 128 + l * 2) = u;
}

// ---------------- QKV projection
__global__ void k_gemm_qkv(const unsigned short* __restrict__ A, const unsigned short* __restrict__ Bt,
                           unsigned short* __restrict__ qkv) {
  __shared__ __align__(16) unsigned short As[128 * 128];
  __shared__ __align__(16) unsigned short Bs[128 * 128];
  int tid = threadIdx.x;
  int m0 = blockIdx.x * 128, n0 = blockIdx.y * 128;
  int sg = tid & 15, sr = tid >> 4;
#pragma unroll
  for (int i = 0; i < 8; i++) {
    int r = sr + i * 16;
    *reinterpret_cast<bf16x8*>(&As[r * 128 + ((sg ^ (r & 7)) << 3)]) =
        *reinterpret_cast<const bf16x8*>(A + (size_t)(m0 + r) * 128 + sg * 8);
    *reinterpret_cast<bf16x8*>(&Bs[r * 128 + ((sg ^ (r & 7)) << 3)]) =
        *reinterpret_cast<const bf16x8*>(Bt + (size_t)(n0 + r) * 128 + sg * 8);
  }
  __syncthreads();
  int l = tid & 63, w = tid >> 6, wmi = w >> 1, wni = w & 1;
  int ln = l & 31, hi = l >> 5;
  f32x16 acc[2][2];
  acc[0][0] = zero16(); acc[0][1] = zero16(); acc[1][0] = zero16(); acc[1][1] = zero16();
#pragma unroll
  for (int kk = 0; kk < 8; kk++) {
    bf16x8 a0 = frag256(As, wmi * 64, l, kk);
    bf16x8 a1 = frag256(As, wmi * 64 + 32, l, kk);
    bf16x8 b0 = frag256(Bs, wni * 64, l, kk);
    bf16x8 b1 = frag256(Bs, wni * 64 + 32, l, kk);
    acc[0][0] = MFMA(a0, b0, acc[0][0]);
    acc[0][1] = MFMA(a0, b1, acc[0][1]);
    acc[1][0] = MFMA(a1, b0, acc[1][0]);
    acc[1][1] = MFMA(a1, b1, acc[1][1]);
  }
  unsigned short* mat = qkv + (size_t)blockIdx.y * 524288;
#pragma unroll
  for (int im = 0; im < 2; im++)
#pragma unroll
    for (int in_ = 0; in_ < 2; in_++) {
      int c = wni * 64 + in_ * 32 + ln;
      int h = c >> 4, d = c & 15;
#pragma unroll
      for (int r = 0; r < 16; r++) {
        int m = m0 + wmi * 64 + im * 32 + (r & 3) + ((r >> 2) << 3) + (hi << 2);
        int bb = m >> 11, tt = m & 2047;
        mat[((size_t)((bb << 3) + h) * 2048 + tt) * 16 + d] = f2bf(acc[im][in_][r]);
      }
    }
}

// ---------------- MFMA flash attention (swapped QK^T, transposed PV) ----------------
DEV bf16x8 pfrag(float a0, float a1, float a2, float a3,
                 float a4, float a5, float a6, float a7) {
  unsigned c0, c1, c2, c3;
  asm("v_cvt_pk_bf16_f32 %0, %1, %2" : "=v"(c0) : "v"(a0), "v"(a1));
  asm("v_cvt_pk_bf16_f32 %0, %1, %2" : "=v"(c1) : "v"(a2), "v"(a3));
  asm("v_cvt_pk_bf16_f32 %0, %1, %2" : "=v"(c2) : "v"(a4), "v"(a5));
  asm("v_cvt_pk_bf16_f32 %0, %1, %2" : "=v"(c3) : "v"(a6), "v"(a7));
  asm("v_permlane32_swap_b32 %0, %1" : "+v"(c0), "+v"(c2));
  asm("v_permlane32_swap_b32 %0, %1" : "+v"(c1), "+v"(c3));
  int4 ri = make_int4((int)c0, (int)c1, (int)c2, (int)c3);
  return *reinterpret_cast<bf16x8*>(&ri);
}

__global__ void __launch_bounds__(256)
k_attn2(const unsigned short* __restrict__ qw, const unsigned short* __restrict__ kw,
        const unsigned short* __restrict__ vw, unsigned short* __restrict__ ow) {
  __shared__ __align__(16) unsigned short vt[2][16][72];  // V^T, padded rows (2-way banks)
  int tid = threadIdx.x;
  int qb = (int)gridDim.x - 1 - (int)blockIdx.x;  // heaviest q-tiles first
  int bh = blockIdx.y;
  int w = tid >> 6, l = tid & 63, ln = l & 31, hi = l >> 5;
  int q0 = qb * 128 + w * 32;
  int q = q0 + ln;
  const float SC = 0.08838834764831845f * 1.4426950408889634f;  // E^-0.5 * log2(e)
  const unsigned short* kbase = kw + (size_t)bh * 32768;
  const unsigned short* vbase = vw + (size_t)bh * 32768;
  // Q as B-operand: lane holds Q[q0+ln][hi*8 + i]
  bf16x8 qf = *reinterpret_cast<const bf16x8*>(qw + (size_t)bh * 32768 + (size_t)q * 16 + hi * 8);
  f32x16 acc = zero16();
  float mr = -1e30f, ls = 0.f;
  int ntiles = 2 * qb + 2;
  int skey = tid >> 1, sh = tid & 1;
  for (int st = 0; st < ntiles; st++) {
    int k0 = st * 64;
    int buf = st & 1;
    if (tid < 128) {  // stage V^T [16][64] for this tile
      const unsigned* vp = reinterpret_cast<const unsigned*>(vbase + (size_t)(k0 + skey) * 16 + sh * 8);
      unsigned u0 = vp[0], u1 = vp[1], u2 = vp[2], u3 = vp[3];
      int d0 = sh * 8;
      vt[buf][d0 + 0][skey] = (unsigned short)u0;
      vt[buf][d0 + 1][skey] = (unsigned short)(u0 >> 16);
      vt[buf][d0 + 2][skey] = (unsigned short)u1;
      vt[buf][d0 + 3][skey] = (unsigned short)(u1 >> 16);
      vt[buf][d0 + 4][skey] = (unsigned short)u2;
      vt[buf][d0 + 5][skey] = (unsigned short)(u2 >> 16);
      vt[buf][d0 + 6][skey] = (unsigned short)u3;
      vt[buf][d0 + 7][skey] = (unsigned short)(u3 >> 16);
    }
    __syncthreads();
    if (k0 > q0 + 31) continue;            // this wave's q-range done with these keys
    bool d1 = (k0 + 32 <= q0 + 31);        // need second 32-key subtile?
    f32x16 p0, p1;
    {
      bf16x8 ka = *reinterpret_cast<const bf16x8*>(kbase + (size_t)(k0 + ln) * 16 + hi * 8);
      p0 = MFMA(ka, qf, zero16());         // S^T: col=q, rows=keys
    }
    if (d1) {
      bf16x8 kb = *reinterpret_cast<const bf16x8*>(kbase + (size_t)(k0 + 32 + ln) * 16 + hi * 8);
      p1 = MFMA(kb, qf, zero16());
    }
    if (k0 + 31 > q0) {                    // subtile 1 overlaps diagonal: causal mask
#pragma unroll
      for (int r = 0; r < 16; r++) {
        int krow = (r & 3) + 8 * (r >> 2) + 4 * hi;
        if (k0 + krow > q) p0[r] = -1e30f;
      }
    }
    if (d1 && (k0 + 63 > q0)) {            // subtile 2 overlaps diagonal: causal mask
#pragma unroll
      for (int r = 0; r < 16; r++) {
        int krow = (r & 3) + 8 * (r >> 2) + 4 * hi;
        if (k0 + 32 + krow > q) p1[r] = -1e30f;
      }
    }
    // online softmax (raw scores; scale folded into exp2 arg)
    float tm = p0[0];
#pragma unroll
    for (int r = 1; r < 16; r++) tm = fmaxf(tm, p0[r]);
    if (d1) {
#pragma unroll
      for (int r = 0; r < 16; r++) tm = fmaxf(tm, p1[r]);
    }
    tm = fmaxf(tm, __shfl_xor(tm, 32, 64));
    if (tm > mr) {
      float corr = exp2f((mr - tm) * SC);
      ls *= corr;
#pragma unroll
      for (int r = 0; r < 8; r++) acc[r] *= corr;
      mr = tm;
    }
    float msc = mr * SC;
#pragma unroll
    for (int r = 0; r < 16; r++) {
      p0[r] = exp2f(fmaf(p0[r], SC, -msc));
      ls += p0[r];
    }
    if (d1) {
#pragma unroll
      for (int r = 0; r < 16; r++) {
        p1[r] = exp2f(fmaf(p1[r], SC, -msc));
        ls += p1[r];
      }
    }
    // PV: O^T += V^T * P^T  (A rows 16-31 duplicate d&15; D rows 16-31 unused)
    const unsigned short* vrow = &vt[buf][ln & 15][0];
    {
      bf16x8 pa = pfrag(p0[0], p0[1], p0[2], p0[3], p0[4], p0[5], p0[6], p0[7]);
      bf16x8 va = *reinterpret_cast<const bf16x8*>(vrow + hi * 8);
      acc = MFMA(va, pa, acc);
      pa = pfrag(p0[8], p0[9], p0[10], p0[11], p0[12], p0[13], p0[14], p0[15]);
      va = *reinterpret_cast<const bf16x8*>(vrow + 16 + hi * 8);
      acc = MFMA(va, pa, acc);
    }
    if (d1) {
      bf16x8 pa = pfrag(p1[0], p1[1], p1[2], p1[3], p1[4], p1[5], p1[6], p1[7]);
      bf16x8 va = *reinterpret_cast<const bf16x8*>(vrow + 32 + hi * 8);
      acc = MFMA(va, pa, acc);
      pa = pfrag(p1[8], p1[9], p1[10], p1[11], p1[12], p1[13], p1[14], p1[15]);
      va = *reinterpret_cast<const bf16x8*>(vrow + 48 + hi * 8);
      acc = MFMA(va, pa, acc);
    }
  }
  ls += __shfl_xor(ls, 32, 64);
  float rl = 1.0f / ls;
  int b_ = bh >> 3, h_ = bh & 7;
  unsigned short* op = ow + ((size_t)(b_ * 2048 + q)) * 128 + h_ * 16;
  int dbase = 4 * hi;  // acc rows r=0..7 -> d = (r&3) + 8*(r>>2) + 4*hi
  unsigned o0 = ((unsigned)f2bf(acc[1] * rl) << 16) | (unsigned)f2bf(acc[0] * rl);
  unsigned o1 = ((unsigned)f2bf(acc[3] * rl) << 16) | (unsigned)f2bf(acc[2] * rl);
  unsigned o2 = ((unsigned)f2bf(acc[5] * rl) << 16) | (unsigned)f2bf(acc[4] * rl);
  unsigned o3 = ((unsigned)f2bf(acc[7] * rl) << 16) | (unsigned)f2bf(acc[6] * rl);
  *reinterpret_cast<unsigned*>(op + dbase) = o0;
  *reinterpret_cast<unsigned*>(op + dbase + 2) = o1;
  *reinterpret_cast<unsigned*>(op + 8 + dbase) = o2;
  *reinterpret_cast<unsigned*>(op + 8 + dbase + 2) = o3;
}

// ---------------- output projection + residual
__global__ void k_gemm_proj(const unsigned short* __restrict__ A, const unsigned short* __restrict__ Bt,
                            const float* __restrict__ bo, const float* __restrict__ x,
                            const float* __restrict__ bf2, float* __restrict__ x1,
                            float* __restrict__ outp) {
  __shared__ __align__(16) unsigned short As[128 * 128];
  __shared__ __align__(16) unsigned short Bs[128 * 128];
  int tid = threadIdx.x;
  int m0 = blockIdx.x * 128;
  int sg = tid & 15, sr = tid >> 4;
#pragma unroll
  for (int i = 0; i < 8; i++) {
    int r = sr + i * 16;
    *reinterpret_cast<bf16x8*>(&As[r * 128 + ((sg ^ (r & 7)) << 3)]) =
        *reinterpret_cast<const bf16x8*>(A + (size_t)(m0 + r) * 128 + sg * 8);
    *reinterpret_cast<bf16x8*>(&Bs[r * 128 + ((sg ^ (r & 7)) << 3)]) =
        *reinterpret_cast<const bf16x8*>(Bt + (size_t)r * 128 + sg * 8);
  }
  __syncthreads();
  int l = tid & 63, w = tid >> 6, wmi = w >> 1, wni = w & 1;
  int ln = l & 31, hi = l >> 5;
  f32x16 acc[2][2];
  acc[0][0] = zero16(); acc[0][1] = zero16(); acc[1][0] = zero16(); acc[1][1] = zero16();
#pragma unroll
  for (int kk = 0; kk < 8; kk++) {
    bf16x8 a0 = frag256(As, wmi * 64, l, kk);
    bf16x8 a1 = frag256(As, wmi * 64 + 32, l, kk);
    bf16x8 b0 = frag256(Bs, wni * 64, l, kk);
    bf16x8 b1 = frag256(Bs, wni * 64 + 32, l, kk);
    acc[0][0] = MFMA(a0, b0, acc[0][0]);
    acc[0][1] = MFMA(a0, b1, acc[0][1]);
    acc[1][0] = MFMA(a1, b0, acc[1][0]);
    acc[1][1] = MFMA(a1, b1, acc[1][1]);
  }
#pragma unroll
  for (int im = 0; im < 2; im++)
#pragma unroll
    for (int in_ = 0; in_ < 2; in_++) {
      int n = wni * 64 + in_ * 32 + ln;
      float bon = bo[n], b2n = bf2[n];
#pragma unroll
      for (int r = 0; r < 16; r++) {
        int m = m0 + wmi * 64 + im * 32 + (r & 3) + ((r >> 2) << 3) + (hi << 2);
        float v = acc[im][in_][r] + bon;
        float xv = x[(size_t)m * 128 + n] + v;
        x1[(size_t)m * 128 + n] = xv;
        outp[(size_t)m * 128 + n] = xv + b2n;
      }
    }
}

// ---------------- fused FFN: out += relu(h2@W1+bf1)@W2 ; split-K over hidden with atomics
__global__ void __launch_bounds__(256, 2)
k_ffn(const unsigned short* __restrict__ h2, const unsigned short* __restrict__ w1t,
      const unsigned short* __restrict__ w2t, const float* __restrict__ bf1,
      float* __restrict__ outp) {
  __shared__ __align__(16) unsigned short w1_lds[64 * 128];
  __shared__ __align__(16) unsigned short w2_lds[128 * 64];
  __shared__ __align__(16) unsigned short g_lds[128 * 64];
  int tid = threadIdx.x, l = tid & 63, w = tid >> 6;
  int wmi = w >> 1, wni = w & 1;
  int ln = l & 31, hi = l >> 5;
  int chunk = blockIdx.x & 15, rowblk = blockIdx.x >> 4;

  bf16x8 af[2][8];
#pragma unroll
  for (int im = 0; im < 2; im++) {
    int row = rowblk * 128 + wmi * 64 + im * 32 + ln;
#pragma unroll
    for (int kk = 0; kk < 8; kk++)
      af[im][kk] = *reinterpret_cast<const bf16x8*>(h2 + (size_t)row * 128 + kk * 16 + hi * 8);
  }

  f32x16 acc2[2][2];
  acc2[0][0] = zero16(); acc2[0][1] = zero16(); acc2[1][0] = zero16(); acc2[1][1] = zero16();

  int sg1 = tid & 15, sr1 = tid >> 4;
  int sg2 = tid & 7, sr2 = tid >> 3;

  for (int it = 0; it < 64; it++) {
    int hid0 = chunk * 4096 + it * 64;
#pragma unroll
    for (int i = 0; i < 4; i++) {
      int r = sr1 + i * 16;
      *reinterpret_cast<bf16x8*>(&w1_lds[r * 128 + ((sg1 ^ (r & 7)) << 3)]) =
          *reinterpret_cast<const bf16x8*>(w1t + (size_t)(hid0 + r) * 128 + sg1 * 8);
    }
#pragma unroll
    for (int i = 0; i < 4; i++) {
      int r = sr2 + i * 32;
      *reinterpret_cast<bf16x8*>(&w2_lds[r * 64 + ((sg2 ^ (r & 7)) << 3)]) =
          *reinterpret_cast<const bf16x8*>(w2t + (size_t)r * 65536 + hid0 + sg2 * 8);
    }
    __syncthreads();

    f32x16 acc1[2];
    acc1[0] = zero16(); acc1[1] = zero16();
#pragma unroll
    for (int kk = 0; kk < 8; kk++) {
      bf16x8 b = frag256(w1_lds, wni * 32, l, kk);
      acc1[0] = MFMA(af[0][kk], b, acc1[0]);
      acc1[1] = MFMA(af[1][kk], b, acc1[1]);
    }
    float b1v = bf1[hid0 + wni * 32 + ln];
    int gn = wni * 32 + ln;
    int ggr = gn >> 3, gof = gn & 7;
#pragma unroll
    for (int im = 0; im < 2; im++) {
#pragma unroll
      for (int r = 0; r < 16; r++) {
        int m = wmi * 64 + im * 32 + (r & 3) + ((r >> 2) << 3) + (hi << 2);
        float v = acc1[im][r] + b1v;
        v = v > 0.f ? v : 0.f;
        g_lds[m * 64 + ((ggr ^ (m & 7)) << 3) + gof] = f2bf(v);
      }
    }
    __syncthreads();

#pragma unroll
    for (int kk = 0; kk < 4; kk++) {
      bf16x8 a0 = frag128(g_lds, wmi * 64, l, kk);
      bf16x8 a1 = frag128(g_lds, wmi * 64 + 32, l, kk);
      bf16x8 b0 = frag128(w2_lds, wni * 64, l, kk);
      bf16x8 b1 = frag128(w2_lds, wni * 64 + 32, l, kk);
      acc2[0][0] = MFMA(a0, b0, acc2[0][0]);
      acc2[0][1] = MFMA(a0, b1, acc2[0][1]);
      acc2[1][0] = MFMA(a1, b0, acc2[1][0]);
      acc2[1][1] = MFMA(a1, b1, acc2[1][1]);
    }
    __syncthreads();
  }

#pragma unroll
  for (int im = 0; im < 2; im++)
#pragma unroll
    for (int in_ = 0; in_ < 2; in_++) {
      int n = wni * 64 + in_ * 32 + ln;
#pragma unroll
      for (int r = 0; r < 16; r++) {
        int m = rowblk * 128 + wmi * 64 + im * 32 + (r & 3) + ((r >> 2) << 3) + (hi << 2);
        atomicAdd(&outp[(size_t)m * 128 + n], acc2[im][in_][r]);
      }
    }
}

extern "C" void kernel_launch(void* const* d_in, const int* in_sizes, int n_in,
                              void* d_out, int out_size, void* d_ws, size_t ws_size,
                              hipStream_t stream) {
  (void)in_sizes; (void)n_in; (void)out_size; (void)ws_size;
  const float* x = (const float*)d_in[0];
  const float* Wk = (const float*)d_in[1];
  const float* Wq = (const float*)d_in[2];
  const float* Wv = (const float*)d_in[3];
  const float* Wo = (const float*)d_in[4];
  const float* bo = (const float*)d_in[5];
  const float* g1 = (const float*)d_in[6];
  const float* be1 = (const float*)d_in[7];
  const float* g2 = (const float*)d_in[8];
  const float* be2 = (const float*)d_in[9];
  const float* W1 = (const float*)d_in[10];
  const float* bf1 = (const float*)d_in[11];
  const float* W2 = (const float*)d_in[12];
  const float* bf2 = (const float*)d_in[13];
  float* outp = (float*)d_out;

  unsigned short* ws = (unsigned short*)d_ws;
  unsigned short* W1t = ws;                       // [65536][128] bf16
  unsigned short* W2t = ws + 8388608;             // [128][65536] bf16
  unsigned short* Wqkvt = ws + 16777216;          // [384][128]
  unsigned short* Wot = ws + 16826368;            // [128][128]
  unsigned short* h1 = ws + 16842752;             // [4096][128]
  unsigned short* h2 = ws + 17367040;             // [4096][128]
  unsigned short* qw = ws + 17891328;             // [16][2048][16]
  unsigned short* kw = ws + 18415616;
  unsigned short* vw = ws + 18939904;
  unsigned short* ow = ws + 19464192;             // [4096][128]
  float* x1 = (float*)(ws + 19988480);            // [4096][128] f32

  k_transpose<<<dim3(2048, 4), dim3(32, 8), 0, stream>>>(W1, W1t, 128, 65536);
  k_transpose<<<dim3(4, 2048), dim3(32, 8), 0, stream>>>(W2, W2t, 65536, 128);
  k_build_qkvo<<<256, 256, 0, stream>>>(Wq, Wk, Wv, Wo, Wqkvt, Wot);
  k_ln<<<1024, 256, 0, stream>>>(x, g1, be1, h1);
  k_gemm_qkv<<<dim3(32, 3), 256, 0, stream>>>(h1, Wqkvt, qw);
  k_attn2<<<dim3(16, 16), 256, 0, stream>>>(qw, kw, vw, ow);
  k_gemm_proj<<<32, 256, 0, stream>>>(ow, Wot, bo, x, bf2, x1, outp);
  k_ln<<<1024, 256, 0, stream>>>(x1, g2, be2, h2);
  k_ffn<<<512, 256, 0, stream>>>(h2, W1t, W2t, bf1, outp);
}